// Round 1
// baseline (105.103 us; speedup 1.0000x reference)
//
#include <hip/hip_runtime.h>
#include <hip/hip_bf16.h>

#define P 128
#define NH 16
#define POS_BND 102
#define RPE_NUM 205          // 2*POS_BND+1
#define TROWS (3 * RPE_NUM)  // 615
#define TPAD 20              // table row pad: 80B rows, 16B aligned, bank-spread
#define ROWS_PER_BLOCK 16

__global__ __launch_bounds__(256)
void rpe_kernel(const int* __restrict__ xyz, const float* __restrict__ table,
                float* __restrict__ out) {
    __shared__ float lt[TROWS * TPAD];   // 49200 B
    __shared__ float sums[NH][P];        // 8192 B  (total 57392 B LDS)

    const int t = threadIdx.x;

    // ---- stage rpe_table into LDS: 615 rows x 16 floats, padded to 20 ----
    // 615*4 = 2460 float4 chunks
    for (int f = t; f < TROWS * 4; f += 256) {
        int row = f >> 2, q = f & 3;
        float4 v = reinterpret_cast<const float4*>(table)[row * 4 + q];
        *reinterpret_cast<float4*>(&lt[row * TPAD + q * 4]) = v;
    }
    __syncthreads();

    const int r0 = blockIdx.x * ROWS_PER_BLOCK;   // global row = b*128 + i
    const int j    = t & 127;    // position within row
    const int half = t >> 7;     // 0: heads 0..7, 1: heads 8..15
    const int hb   = half * 8;

    // software-prefetch xyz for the first row
    int nx0, nx1, nx2;
    {
        const int* xp = xyz + ((size_t)r0 * P + j) * 3;
        nx0 = xp[0]; nx1 = xp[1]; nx2 = xp[2];
    }

    for (int rr = 0; rr < ROWS_PER_BLOCK; ++rr) {
        const int r = r0 + rr;
        const int b = r >> 7;
        const int i = r & 127;

        int x0 = nx0, x1 = nx1, x2 = nx2;
        if (rr + 1 < ROWS_PER_BLOCK) {
            const int* xp = xyz + ((size_t)(r + 1) * P + j) * 3;
            nx0 = xp[0]; nx1 = xp[1]; nx2 = xp[2];
        }

        // ---- phase 1: clamp -> gather -> per-(j, 8 heads) sums ----
        int i0 = min(max(x0, -POS_BND), POS_BND) + POS_BND;
        int i1 = min(max(x1, -POS_BND), POS_BND) + POS_BND + RPE_NUM;
        int i2 = min(max(x2, -POS_BND), POS_BND) + POS_BND + 2 * RPE_NUM;

        const float* p0 = &lt[i0 * TPAD + hb];
        const float* p1 = &lt[i1 * TPAD + hb];
        const float* p2 = &lt[i2 * TPAD + hb];
        float4 a0 = *(const float4*)p0, b0 = *(const float4*)(p0 + 4);
        float4 a1 = *(const float4*)p1, b1 = *(const float4*)(p1 + 4);
        float4 a2 = *(const float4*)p2, b2 = *(const float4*)(p2 + 4);

        sums[hb + 0][j] = a0.x + a1.x + a2.x;
        sums[hb + 1][j] = a0.y + a1.y + a2.y;
        sums[hb + 2][j] = a0.z + a1.z + a2.z;
        sums[hb + 3][j] = a0.w + a1.w + a2.w;
        sums[hb + 4][j] = b0.x + b1.x + b2.x;
        sums[hb + 5][j] = b0.y + b1.y + b2.y;
        sums[hb + 6][j] = b0.z + b1.z + b2.z;
        sums[hb + 7][j] = b0.w + b1.w + b2.w;

        __syncthreads();

        // ---- phase 2: coalesced float4 stores, out[b][h][i][0..127] ----
        // 16 heads * 32 float4 = 512 chunks, 2 iterations of 256 threads
        #pragma unroll
        for (int it = 0; it < 2; ++it) {
            int q  = it * 256 + t;     // 0..511
            int j4 = q & 31;           // float4 index within row
            int h  = q >> 5;           // 0..15
            float4 v = *reinterpret_cast<const float4*>(&sums[h][j4 * 4]);
            size_t o = ((((size_t)b * NH + h) * P + i) * P) + (size_t)j4 * 4;
            *reinterpret_cast<float4*>(out + o) = v;
        }

        __syncthreads();   // protect sums reuse next row
    }
}

extern "C" void kernel_launch(void* const* d_in, const int* in_sizes, int n_in,
                              void* d_out, int out_size, void* d_ws, size_t ws_size,
                              hipStream_t stream) {
    const int*   xyz   = (const int*)d_in[0];
    const float* table = (const float*)d_in[1];
    float*       out   = (float*)d_out;

    const int total_rows = 256 * P;                    // 32768
    const int grid = total_rows / ROWS_PER_BLOCK;      // 2048
    rpe_kernel<<<grid, 256, 0, stream>>>(xyz, table, out);
}

// Round 2
// 76.568 us; speedup vs baseline: 1.3727x; 1.3727x over previous
//
#include <hip/hip_runtime.h>
#include <hip/hip_bf16.h>

#define P 128
#define NH 16
#define POS_BND 102
#define RPE_NUM 205          // 2*POS_BND+1
#define TROWS (3 * RPE_NUM)  // 615
#define TSTRIDE 12           // dwords per padded table row (8 data + 4 pad) = 48 B
#define SWS 68               // sums row stride in dwords (17*4 -> conflict-free both sides)
#define ROWS_PER_BLOCK 16

__device__ __forceinline__ float blo(unsigned d) { return __uint_as_float(d << 16); }
__device__ __forceinline__ float bhi(unsigned d) { return __uint_as_float(d & 0xffff0000u); }

__global__ __launch_bounds__(256)
void rpe_kernel(const int* __restrict__ xyz, const float* __restrict__ table,
                float* __restrict__ out) {
    __shared__ unsigned lt[TROWS * TSTRIDE];   // 29520 B, bf16-packed table
    __shared__ float sw[4][NH][SWS];           // 17408 B, per-wave transpose buffers

    const int t = threadIdx.x;
    const int w = t >> 6;    // wave id 0..3
    const int l = t & 63;    // lane

    // ---- stage rpe_table into LDS as packed bf16 (round-half-up) ----
    // 615 rows * 8 packed dwords = 4920
    for (int q = t; q < TROWS * 8; q += 256) {
        int row = q >> 3, d = q & 7;
        float2 v = reinterpret_cast<const float2*>(table)[row * 8 + d];
        unsigned a = __float_as_uint(v.x), b = __float_as_uint(v.y);
        a = (a + 0x8000u) >> 16;
        b = (b + 0x8000u) & 0xffff0000u;
        lt[row * TSTRIDE + d] = a | b;
    }
    __syncthreads();   // the ONLY block-wide barrier

    const int r0 = blockIdx.x * ROWS_PER_BLOCK;

    // wave w independently processes 8 tasks: rows r0+4w..r0+4w+3, j-halves {0,1}
    // prefetch xyz for first task
    int x0, x1, x2;
    {
        const int* xp = xyz + (((size_t)(r0 + 4 * w) * P) + l) * 3;
        x0 = xp[0]; x1 = xp[1]; x2 = xp[2];
    }

    for (int k = 0; k < 8; ++k) {
        const int rr = 4 * w + (k >> 1);
        const int jh = k & 1;
        const int r  = r0 + rr;
        const int b  = r >> 7;
        const int i  = r & 127;
        const int jbase = jh * 64;

        int y0 = x0, y1 = x1, y2 = x2;
        if (k < 7) {   // prefetch next task's xyz
            const int rn = r0 + 4 * w + ((k + 1) >> 1);
            const int jn = ((k + 1) & 1) * 64;
            const int* xp = xyz + (((size_t)rn * P) + jn + l) * 3;
            x0 = xp[0]; x1 = xp[1]; x2 = xp[2];
        }

        // ---- clamp -> table indices ----
        const int i0 = min(max(y0, -POS_BND), POS_BND) + POS_BND;
        const int i1 = min(max(y1, -POS_BND), POS_BND) + POS_BND + RPE_NUM;
        const int i2 = min(max(y2, -POS_BND), POS_BND) + POS_BND + 2 * RPE_NUM;

        // ---- gather: 6 x ds_read_b128 (16 heads x 3 axes, bf16) ----
        uint4 a0 = *reinterpret_cast<const uint4*>(&lt[i0 * TSTRIDE]);
        uint4 a1 = *reinterpret_cast<const uint4*>(&lt[i0 * TSTRIDE + 4]);
        uint4 b0 = *reinterpret_cast<const uint4*>(&lt[i1 * TSTRIDE]);
        uint4 b1 = *reinterpret_cast<const uint4*>(&lt[i1 * TSTRIDE + 4]);
        uint4 c0 = *reinterpret_cast<const uint4*>(&lt[i2 * TSTRIDE]);
        uint4 c1 = *reinterpret_cast<const uint4*>(&lt[i2 * TSTRIDE + 4]);

        // ---- unpack bf16 -> f32, sum 3 axes, transpose-write into sw[w] ----
        // write: sw[w][h][l], bank = (4h + l) mod 32 -> 2-way (free)
        float* swp = &sw[w][0][l];
#define EMIT(hh, da, db, dc)                                        \
        swp[(2*(hh))*SWS]   = blo(da) + blo(db) + blo(dc);          \
        swp[(2*(hh)+1)*SWS] = bhi(da) + bhi(db) + bhi(dc);
        EMIT(0, a0.x, b0.x, c0.x)
        EMIT(1, a0.y, b0.y, c0.y)
        EMIT(2, a0.z, b0.z, c0.z)
        EMIT(3, a0.w, b0.w, c0.w)
        EMIT(4, a1.x, b1.x, c1.x)
        EMIT(5, a1.y, b1.y, c1.y)
        EMIT(6, a1.z, b1.z, c1.z)
        EMIT(7, a1.w, b1.w, c1.w)
#undef EMIT

        // ---- read back (float4, banks tile evenly) + coalesced stores ----
        // same-wave producer/consumer: compiler inserts lgkmcnt wait; no barrier.
        const size_t obase = (((size_t)b * NH) * P + i) * P + jbase;
#pragma unroll
        for (int it = 0; it < 4; ++it) {
            int h  = it * 4 + (l >> 4);
            int j4 = l & 15;
            float4 v = *reinterpret_cast<const float4*>(&sw[w][h][j4 * 4]);
            *reinterpret_cast<float4*>(out + obase + (size_t)h * (P * P) + j4 * 4) = v;
        }
    }
}

extern "C" void kernel_launch(void* const* d_in, const int* in_sizes, int n_in,
                              void* d_out, int out_size, void* d_ws, size_t ws_size,
                              hipStream_t stream) {
    const int*   xyz   = (const int*)d_in[0];
    const float* table = (const float*)d_in[1];
    float*       out   = (float*)d_out;

    const int total_rows = 256 * P;                   // 32768
    const int grid = total_rows / ROWS_PER_BLOCK;     // 2048
    rpe_kernel<<<grid, 256, 0, stream>>>(xyz, table, out);
}

// Round 4
// 57.644 us; speedup vs baseline: 1.8233x; 1.3283x over previous
//
#include <hip/hip_runtime.h>
#include <hip/hip_bf16.h>

#define P 128
#define NH 16
#define POS_BND 102
#define RPE_NUM 205          // 2*POS_BND+1
#define TROWS (3 * RPE_NUM)  // 615
#define TSTRIDE 12           // bf16-packed table row stride in dwords (48 B, 16B-aligned, 8 bank starts)
#define SWS 68               // f32 transpose row stride (conflict-free write + readback)
#define ROWS_PER_BLOCK 16

typedef float floatx4 __attribute__((ext_vector_type(4)));   // native vector: OK for NT store

__device__ __forceinline__ float blo(unsigned d) { return __uint_as_float(d << 16); }
__device__ __forceinline__ float bhi(unsigned d) { return __uint_as_float(d & 0xffff0000u); }

__global__ __launch_bounds__(256)
void rpe_kernel(const int* __restrict__ xyz, const float* __restrict__ table,
                float* __restrict__ out) {
    __shared__ unsigned lt[TROWS * TSTRIDE];   // 29520 B, bf16-packed table
    __shared__ float sw[4][8][SWS];            // 8704 B per-wave half-transpose buffers
                                               // total 38224 B -> 4 blocks/CU (16 waves)

    const int t = threadIdx.x;
    const int w = t >> 6;    // wave id 0..3
    const int l = t & 63;    // lane

    // ---- stage rpe_table into LDS as packed bf16 (round-half-up) ----
    for (int q = t; q < TROWS * 8; q += 256) {
        int row = q >> 3, d = q & 7;
        float2 v = reinterpret_cast<const float2*>(table)[row * 8 + d];
        unsigned a = (__float_as_uint(v.x) + 0x8000u) >> 16;
        unsigned b = (__float_as_uint(v.y) + 0x8000u) & 0xffff0000u;
        lt[row * TSTRIDE + d] = a | b;
    }
    __syncthreads();   // the ONLY block-wide barrier

    const int r0 = blockIdx.x * ROWS_PER_BLOCK;

    // wave w: 8 (row, j-half) pairs; rows r0+4w .. r0+4w+3
    int x0, x1, x2;
    {
        const int* xp = xyz + (((size_t)(r0 + 4 * w) * P) + l) * 3;
        x0 = xp[0]; x1 = xp[1]; x2 = xp[2];
    }

    for (int k = 0; k < 8; ++k) {
        const int r  = r0 + 4 * w + (k >> 1);
        const int jh = k & 1;
        const int b  = r >> 7;
        const int i  = r & 127;

        int y0 = x0, y1 = x1, y2 = x2;
        if (k < 7) {   // prefetch next pair's xyz
            const int rn = r0 + 4 * w + ((k + 1) >> 1);
            const int jn = ((k + 1) & 1) * 64;
            const int* xp = xyz + (((size_t)rn * P) + jn + l) * 3;
            x0 = xp[0]; x1 = xp[1]; x2 = xp[2];
        }

        const int i0 = min(max(y0, -POS_BND), POS_BND) + POS_BND;
        const int i1 = min(max(y1, -POS_BND), POS_BND) + POS_BND + RPE_NUM;
        const int i2 = min(max(y2, -POS_BND), POS_BND) + POS_BND + 2 * RPE_NUM;

        const size_t obase = (((size_t)b * NH) * P + i) * P + (size_t)(jh * 64);
        float* swp = &sw[w][0][l];

        // two half-tasks of 8 heads each; DS queue pipelines them (in-order per wave)
        #pragma unroll
        for (int hh = 0; hh < 2; ++hh) {
            // gather: 3 x ds_read_b128 (8 heads x 3 axes, bf16)
            uint4 ga = *reinterpret_cast<const uint4*>(&lt[i0 * TSTRIDE + hh * 4]);
            uint4 gb = *reinterpret_cast<const uint4*>(&lt[i1 * TSTRIDE + hh * 4]);
            uint4 gc = *reinterpret_cast<const uint4*>(&lt[i2 * TSTRIDE + hh * 4]);

            // unpack + sum 3 axes -> transpose-write sw[w][hl][l]
            // bank = (4*hl + l) mod 32 -> 2-way (free)
            swp[0*SWS] = blo(ga.x) + blo(gb.x) + blo(gc.x);
            swp[1*SWS] = bhi(ga.x) + bhi(gb.x) + bhi(gc.x);
            swp[2*SWS] = blo(ga.y) + blo(gb.y) + blo(gc.y);
            swp[3*SWS] = bhi(ga.y) + bhi(gb.y) + bhi(gc.y);
            swp[4*SWS] = blo(ga.z) + blo(gb.z) + blo(gc.z);
            swp[5*SWS] = bhi(ga.z) + bhi(gb.z) + bhi(gc.z);
            swp[6*SWS] = blo(ga.w) + blo(gb.w) + blo(gc.w);
            swp[7*SWS] = bhi(ga.w) + bhi(gb.w) + bhi(gc.w);

            // readback (float4-wide, even bank tiling) + coalesced NT stores
            #pragma unroll
            for (int it = 0; it < 2; ++it) {
                int hl = it * 4 + (l >> 4);   // local head 0..7
                int j4 = l & 15;
                floatx4 v = *reinterpret_cast<const floatx4*>(&sw[w][hl][j4 * 4]);
                size_t o = obase + (size_t)(hh * 8 + hl) * (P * P) + (size_t)(j4 * 4);
                __builtin_nontemporal_store(v, reinterpret_cast<floatx4*>(out + o));
            }
        }
    }
}

extern "C" void kernel_launch(void* const* d_in, const int* in_sizes, int n_in,
                              void* d_out, int out_size, void* d_ws, size_t ws_size,
                              hipStream_t stream) {
    const int*   xyz   = (const int*)d_in[0];
    const float* table = (const float*)d_in[1];
    float*       out   = (float*)d_out;

    const int total_rows = 256 * P;                   // 32768
    const int grid = total_rows / ROWS_PER_BLOCK;     // 2048
    rpe_kernel<<<grid, 256, 0, stream>>>(xyz, table, out);
}

// Round 5
// 54.890 us; speedup vs baseline: 1.9148x; 1.0502x over previous
//
#include <hip/hip_runtime.h>
#include <hip/hip_bf16.h>

#define P 128
#define NH 16
#define POS_BND 102
#define RPE_NUM 205            // 2*POS_BND+1
#define TROWS 615              // 3*RPE_NUM
#define HALF_OFF 2460          // uint offset of half-table B (heads 8..15)
#define ROWS_PER_BLOCK 16

typedef float floatx4 __attribute__((ext_vector_type(4)));

__device__ __forceinline__ float blo(unsigned d) { return __uint_as_float(d << 16); }
__device__ __forceinline__ float bhi(unsigned d) { return __uint_as_float(d & 0xffff0000u); }
__device__ __forceinline__ unsigned pkbf(float a, float b) {
    unsigned r;
    asm("v_cvt_pk_bf16_f32 %0, %1, %2" : "=v"(r) : "v"(a), "v"(b));
    return r;   // low16 = bf16(a), high16 = bf16(b)
}

__global__ __launch_bounds__(256, 3)
void rpe_kernel(const int* __restrict__ xyz, const float* __restrict__ table,
                float* __restrict__ out) {
    // two compact half-tables, 16B rows (8 bank-windows for random b128 gathers)
    __shared__ unsigned lt[2 * HALF_OFF];     // 19680 B
    // per-wave transpose buffer: 16 heads x (2 rows x 64 j-pairs) bf16-packed
    __shared__ unsigned su[4][NH][128];       // 32768 B; total 52448 B -> 3 blocks/CU

    const int t = threadIdx.x;
    const int w = t >> 6, l = t & 63;

    // ---- stage table as bf16 pairs: half A = heads 0..7, half B = heads 8..15 ----
    for (int q = t; q < TROWS * 8; q += 256) {
        int row = q >> 3, d = q & 7;
        float2 v = reinterpret_cast<const float2*>(table)[row * 8 + d];
        unsigned a = (__float_as_uint(v.x) + 0x8000u) >> 16;
        unsigned b = (__float_as_uint(v.y) + 0x8000u) & 0xffff0000u;
        int dst = (d < 4) ? (row * 4 + d) : (HALF_OFF + row * 4 + (d - 4));
        lt[dst] = a | b;
    }

    const int r0 = blockIdx.x * ROWS_PER_BLOCK + 4 * w;   // wave's first row
    const int2* xp = reinterpret_cast<const int2*>(xyz);

    // prefetch task 0 (rows r0, r0+1); lane l covers j = 2l, 2l+1 (3 int2 per row)
    int2 p0, p1, p2, p3, p4, p5;
    {
        size_t ba = (size_t)192 * r0 + 3 * l;
        size_t bb = (size_t)192 * (r0 + 1) + 3 * l;
        p0 = xp[ba]; p1 = xp[ba + 1]; p2 = xp[ba + 2];
        p3 = xp[bb]; p4 = xp[bb + 1]; p5 = xp[bb + 2];
    }
    __syncthreads();   // the ONLY barrier (table visibility)

    #pragma unroll
    for (int k = 0; k < 2; ++k) {            // 2 tasks x 2 rows = 4 rows per wave
        const int ra = r0 + 2 * k;           // even -> rows (i, i+1) same b-plane
        const int b  = ra >> 7;
        const int i  = ra & 127;

        int2 c0 = p0, c1 = p1, c2 = p2, c3 = p3, c4 = p4, c5 = p5;
        if (k == 0) {                        // prefetch next task's xyz
            size_t ba = (size_t)192 * (r0 + 2) + 3 * l;
            size_t bb = (size_t)192 * (r0 + 3) + 3 * l;
            p0 = xp[ba]; p1 = xp[ba + 1]; p2 = xp[ba + 2];
            p3 = xp[bb]; p4 = xp[bb + 1]; p5 = xp[bb + 2];
        }

        // ---- compute: 2 row-jobs; lane handles (j0=2l, j1=2l+1) of one row ----
        #pragma unroll
        for (int s = 0; s < 2; ++s) {
            int x0, y0, z0, x1, y1, z1;
            if (s == 0) { x0 = c0.x; y0 = c0.y; z0 = c1.x; x1 = c1.y; y1 = c2.x; z1 = c2.y; }
            else        { x0 = c3.x; y0 = c3.y; z0 = c4.x; x1 = c4.y; y1 = c5.x; z1 = c5.y; }

            int t00 = min(max(x0, -POS_BND), POS_BND) + POS_BND;
            int t01 = min(max(y0, -POS_BND), POS_BND) + POS_BND + RPE_NUM;
            int t02 = min(max(z0, -POS_BND), POS_BND) + POS_BND + 2 * RPE_NUM;
            int t10 = min(max(x1, -POS_BND), POS_BND) + POS_BND;
            int t11 = min(max(y1, -POS_BND), POS_BND) + POS_BND + RPE_NUM;
            int t12 = min(max(z1, -POS_BND), POS_BND) + POS_BND + 2 * RPE_NUM;

            // gathers: j0 half A/B, j1 half A/B  (12 x ds_read_b128)
            uint4 ga0 = *reinterpret_cast<const uint4*>(&lt[t00 * 4]);
            uint4 ga1 = *reinterpret_cast<const uint4*>(&lt[t01 * 4]);
            uint4 ga2 = *reinterpret_cast<const uint4*>(&lt[t02 * 4]);
            uint4 gb0 = *reinterpret_cast<const uint4*>(&lt[HALF_OFF + t00 * 4]);
            uint4 gb1 = *reinterpret_cast<const uint4*>(&lt[HALF_OFF + t01 * 4]);
            uint4 gb2 = *reinterpret_cast<const uint4*>(&lt[HALF_OFF + t02 * 4]);
            uint4 gc0 = *reinterpret_cast<const uint4*>(&lt[t10 * 4]);
            uint4 gc1 = *reinterpret_cast<const uint4*>(&lt[t11 * 4]);
            uint4 gc2 = *reinterpret_cast<const uint4*>(&lt[t12 * 4]);
            uint4 gd0 = *reinterpret_cast<const uint4*>(&lt[HALF_OFF + t10 * 4]);
            uint4 gd1 = *reinterpret_cast<const uint4*>(&lt[HALF_OFF + t11 * 4]);
            uint4 gd2 = *reinterpret_cast<const uint4*>(&lt[HALF_OFF + t12 * 4]);

            // sum 3 axes per head, pack (j0,j1) -> bf16 pair, write su
            // write bank = (s*64+l)%32 -> 2-way (free)
            unsigned* srow = &su[w][0][s * 64 + l];
            srow[ 0*128] = pkbf(blo(ga0.x)+blo(ga1.x)+blo(ga2.x), blo(gc0.x)+blo(gc1.x)+blo(gc2.x));
            srow[ 1*128] = pkbf(bhi(ga0.x)+bhi(ga1.x)+bhi(ga2.x), bhi(gc0.x)+bhi(gc1.x)+bhi(gc2.x));
            srow[ 2*128] = pkbf(blo(ga0.y)+blo(ga1.y)+blo(ga2.y), blo(gc0.y)+blo(gc1.y)+blo(gc2.y));
            srow[ 3*128] = pkbf(bhi(ga0.y)+bhi(ga1.y)+bhi(ga2.y), bhi(gc0.y)+bhi(gc1.y)+bhi(gc2.y));
            srow[ 4*128] = pkbf(blo(ga0.z)+blo(ga1.z)+blo(ga2.z), blo(gc0.z)+blo(gc1.z)+blo(gc2.z));
            srow[ 5*128] = pkbf(bhi(ga0.z)+bhi(ga1.z)+bhi(ga2.z), bhi(gc0.z)+bhi(gc1.z)+bhi(gc2.z));
            srow[ 6*128] = pkbf(blo(ga0.w)+blo(ga1.w)+blo(ga2.w), blo(gc0.w)+blo(gc1.w)+blo(gc2.w));
            srow[ 7*128] = pkbf(bhi(ga0.w)+bhi(ga1.w)+bhi(ga2.w), bhi(gc0.w)+bhi(gc1.w)+bhi(gc2.w));
            srow[ 8*128] = pkbf(blo(gb0.x)+blo(gb1.x)+blo(gb2.x), blo(gd0.x)+blo(gd1.x)+blo(gd2.x));
            srow[ 9*128] = pkbf(bhi(gb0.x)+bhi(gb1.x)+bhi(gb2.x), bhi(gd0.x)+bhi(gd1.x)+bhi(gd2.x));
            srow[10*128] = pkbf(blo(gb0.y)+blo(gb1.y)+blo(gb2.y), blo(gd0.y)+blo(gd1.y)+blo(gd2.y));
            srow[11*128] = pkbf(bhi(gb0.y)+bhi(gb1.y)+bhi(gb2.y), bhi(gd0.y)+bhi(gd1.y)+bhi(gd2.y));
            srow[12*128] = pkbf(blo(gb0.z)+blo(gb1.z)+blo(gb2.z), blo(gd0.z)+blo(gd1.z)+blo(gd2.z));
            srow[13*128] = pkbf(bhi(gb0.z)+bhi(gb1.z)+bhi(gb2.z), bhi(gd0.z)+bhi(gd1.z)+bhi(gd2.z));
            srow[14*128] = pkbf(blo(gb0.w)+blo(gb1.w)+blo(gb2.w), blo(gd0.w)+blo(gd1.w)+blo(gd2.w));
            srow[15*128] = pkbf(bhi(gb0.w)+bhi(gb1.w)+bhi(gb2.w), bhi(gd0.w)+bhi(gd1.w)+bhi(gd2.w));
        }

        // ---- store: per head one fully-contiguous 1KB NT store (rows i, i+1) ----
        // ds_read_b64 at 2l: banks uniformly tiled, conflict-free
        const size_t pbase = ((size_t)b * NH) * (P * P) + (size_t)i * P + 4 * l;
        #pragma unroll
        for (int h = 0; h < NH; ++h) {
            uint2 v = *reinterpret_cast<const uint2*>(&su[w][h][2 * l]);
            floatx4 f = { blo(v.x), bhi(v.x), blo(v.y), bhi(v.y) };
            __builtin_nontemporal_store(f,
                reinterpret_cast<floatx4*>(out + pbase + (size_t)h * (P * P)));
        }
    }
}

extern "C" void kernel_launch(void* const* d_in, const int* in_sizes, int n_in,
                              void* d_out, int out_size, void* d_ws, size_t ws_size,
                              hipStream_t stream) {
    const int*   xyz   = (const int*)d_in[0];
    const float* table = (const float*)d_in[1];
    float*       out   = (float*)d_out;

    const int total_rows = 256 * P;                   // 32768
    const int grid = total_rows / ROWS_PER_BLOCK;     // 2048
    rpe_kernel<<<grid, 256, 0, stream>>>(xyz, table, out);
}